// Round 1
// baseline (2150.369 us; speedup 1.0000x reference)
//
#include <hip/hip_runtime.h>
#include <hip/hip_bf16.h>

#define N_NODES 100000
#define NFEAT 9
#define HID 128
#define B_GRAPHS 64
#define SEQ_LEN 768
#define HD 256
#define L_LAYERS 4
#define LN_EPS 1e-5f

__device__ __forceinline__ float lrelu(float v) { return v > 0.f ? v : 0.2f * v; }

__device__ __forceinline__ float wave_sum64(float x) {
#pragma unroll
  for (int o = 32; o >= 1; o >>= 1) x += __shfl_xor(x, o, 64);
  return x;
}
__device__ __forceinline__ float grp32_sum(float x) {
#pragma unroll
  for (int o = 16; o >= 1; o >>= 1) x += __shfl_xor(x, o, 64);
  return x;
}

// h = relu(x @ ne_W.T + ne_b); thread per (node, col)
__global__ __launch_bounds__(256) void ne_kernel(const float* __restrict__ x,
                                                 const float* __restrict__ W,
                                                 const float* __restrict__ b,
                                                 float* __restrict__ h) {
  int idx = blockIdx.x * 256 + threadIdx.x;
  int n = idx >> 7, c = idx & 127;
  const float* xr = x + n * NFEAT;
  const float* wr = W + c * NFEAT;
  float acc = b[c];
#pragma unroll
  for (int k = 0; k < NFEAT; ++k) acc += xr[k] * wr[k];
  h[idx] = fmaxf(acc, 0.f);
}

__global__ __launch_bounds__(256) void hist_kernel(const int* __restrict__ dst,
                                                   int* __restrict__ cnt, int E) {
  int i = blockIdx.x * 256 + threadIdx.x;
  if (i < E) atomicAdd(&cnt[dst[i]], 1);
}

// single-block chunked exclusive scan (N=100000)
__global__ __launch_bounds__(1024) void exscan_kernel(const int* __restrict__ cnt,
                                                      int* __restrict__ off, int n, int total) {
  __shared__ int wsum[16];
  __shared__ int srun, stot;
  int tid = threadIdx.x, lane = tid & 63, w = tid >> 6;
  if (tid == 0) srun = 0;
  __syncthreads();
  for (int base = 0; base < n; base += 1024) {
    int i = base + tid;
    int v = (i < n) ? cnt[i] : 0;
    int xs = v;
#pragma unroll
    for (int o = 1; o < 64; o <<= 1) {
      int t = __shfl_up(xs, o, 64);
      if (lane >= o) xs += t;
    }
    if (lane == 63) wsum[w] = xs;
    __syncthreads();
    if (tid == 0) {
      int r = 0;
      for (int j = 0; j < 16; ++j) { int t = wsum[j]; wsum[j] = r; r += t; }
      stot = r;
    }
    __syncthreads();
    if (i < n) off[i] = srun + wsum[w] + xs - v;
    __syncthreads();
    if (tid == 0) srun += stot;
    __syncthreads();
  }
  if (tid == 0) off[n] = total;
}

__global__ __launch_bounds__(256) void scatter_kernel(const int* __restrict__ src,
                                                      const int* __restrict__ dst,
                                                      const int* __restrict__ off,
                                                      int* __restrict__ cur,
                                                      int* __restrict__ eadj, int E) {
  int i = blockIdx.x * 256 + threadIdx.x;
  if (i < E) {
    int d = dst[i];
    int pos = atomicAdd(&cur[d], 1);
    eadj[off[d] + pos] = src[i];
  }
}

// xl = h @ W.T (per layer) + per-node head logits e_src/e_dst.
// block = 256 thr = 4 waves, 16 nodes/block; W staged in LDS in two k-halves.
__global__ __launch_bounds__(256) void gat_xl_kernel(const float* __restrict__ h,
                                                     const float* __restrict__ W,
                                                     const float* __restrict__ asrc,
                                                     const float* __restrict__ adst,
                                                     float* __restrict__ xl,
                                                     float* __restrict__ esrc,
                                                     float* __restrict__ edst) {
  __shared__ float Wl[128 * 68];  // pad 64->68 dwords: banks (4c+k)%32, balanced
  __shared__ float hl[16 * 64];
  const int tid = threadIdx.x;
  const int base = blockIdx.x * 16;
  const int lane = tid & 63;
  const int g = tid >> 6;
  const int c0 = lane, c1 = lane + 64;

  float acc[4][2];
#pragma unroll
  for (int nn = 0; nn < 4; ++nn) { acc[nn][0] = 0.f; acc[nn][1] = 0.f; }

  for (int half = 0; half < 2; ++half) {
    // stage W[:, half*64 : half*64+64]
#pragma unroll
    for (int i = 0; i < 8; ++i) {
      int f4 = tid + i * 256;          // 2048 float4
      int c = f4 >> 4;                 // row
      int kk = (f4 & 15) << 2;         // col within half
      float4 w = *(const float4*)(W + c * HID + half * 64 + kk);
      *(float4*)&Wl[c * 68 + kk] = w;
    }
    {
      int row = tid >> 4, kk = (tid & 15) << 2;  // 256 float4
      float4 hv = *(const float4*)(h + (size_t)(base + row) * HID + half * 64 + kk);
      *(float4*)&hl[row * 64 + kk] = hv;
    }
    __syncthreads();
    const float* Wc0 = &Wl[c0 * 68];
    const float* Wc1 = &Wl[c1 * 68];
    const float* hg = &hl[g * 4 * 64];
#pragma unroll
    for (int k0 = 0; k0 < 64; k0 += 4) {
      float4 w0 = *(const float4*)(Wc0 + k0);
      float4 w1 = *(const float4*)(Wc1 + k0);
#pragma unroll
      for (int nn = 0; nn < 4; ++nn) {
        float4 hv = *(const float4*)(hg + nn * 64 + k0);
        acc[nn][0] += hv.x * w0.x + hv.y * w0.y + hv.z * w0.z + hv.w * w0.w;
        acc[nn][1] += hv.x * w1.x + hv.y * w1.y + hv.z * w1.z + hv.w * w1.w;
      }
    }
    __syncthreads();
  }

  const float as0 = asrc[c0], as1 = asrc[c1];
  const float ad0 = adst[c0], ad1 = adst[c1];
#pragma unroll
  for (int nn = 0; nn < 4; ++nn) {
    int node = base + g * 4 + nn;
    xl[(size_t)node * HID + c0] = acc[nn][0];
    xl[(size_t)node * HID + c1] = acc[nn][1];
    float va = grp32_sum(acc[nn][0] * as0);
    float vb = grp32_sum(acc[nn][1] * as1);
    float vc = grp32_sum(acc[nn][0] * ad0);
    float vd = grp32_sum(acc[nn][1] * ad1);
    if ((lane & 31) == 0) {
      int hd = lane >> 5;
      esrc[node * 4 + hd] = va;
      esrc[node * 4 + 2 + hd] = vb;
      edst[node * 4 + hd] = vc;
      edst[node * 4 + 2 + hd] = vd;
    }
  }
}

// per-node (wave-per-node) softmax aggregation + bias + LN + relu + residual
__global__ __launch_bounds__(256) void gat_agg_kernel(const float* __restrict__ xl,
                                                      const float* __restrict__ esrc,
                                                      const float* __restrict__ edst,
                                                      const int* __restrict__ off,
                                                      const int* __restrict__ eadj,
                                                      const float* __restrict__ gbias,
                                                      const float* __restrict__ lng,
                                                      const float* __restrict__ lnb,
                                                      float* __restrict__ h) {
  const int tid = threadIdx.x;
  const int lane = tid & 63;
  const int i = blockIdx.x * 4 + (tid >> 6);
  const int hd0 = lane >> 5;  // head for col c0=lane; col c1=lane+64 -> head hd0+2

  const float4 ed = *(const float4*)(edst + (size_t)i * 4);
  const float4 e0v = *(const float4*)(esrc + (size_t)i * 4);
  float e0 = lrelu(e0v.x + ed.x);
  float e1 = lrelu(e0v.y + ed.y);
  float e2 = lrelu(e0v.z + ed.z);
  float e3 = lrelu(e0v.w + ed.w);
  float m0 = e0, m1 = e1, m2 = e2, m3 = e3;
  const int beg = off[i], end = off[i + 1];
  for (int j = beg; j < end; ++j) {
    int s = eadj[j];
    const float4 es = *(const float4*)(esrc + (size_t)s * 4);
    m0 = fmaxf(m0, lrelu(es.x + ed.x));
    m1 = fmaxf(m1, lrelu(es.y + ed.y));
    m2 = fmaxf(m2, lrelu(es.z + ed.z));
    m3 = fmaxf(m3, lrelu(es.w + ed.w));
  }
  // pass 2: accumulate p and p-weighted messages (self-loop first)
  float p0 = __expf(e0 - m0), p1 = __expf(e1 - m1), p2 = __expf(e2 - m2), p3 = __expf(e3 - m3);
  float s0 = p0, s1 = p1, s2 = p2, s3 = p3;
  float psA = (hd0 == 0) ? p0 : p1;
  float psB = (hd0 == 0) ? p2 : p3;
  float acc0 = xl[(size_t)i * HID + lane] * psA;
  float acc1 = xl[(size_t)i * HID + 64 + lane] * psB;
  for (int j = beg; j < end; ++j) {
    int s = eadj[j];
    const float4 es = *(const float4*)(esrc + (size_t)s * 4);
    float q0 = __expf(lrelu(es.x + ed.x) - m0);
    float q1 = __expf(lrelu(es.y + ed.y) - m1);
    float q2 = __expf(lrelu(es.z + ed.z) - m2);
    float q3 = __expf(lrelu(es.w + ed.w) - m3);
    s0 += q0; s1 += q1; s2 += q2; s3 += q3;
    float qA = (hd0 == 0) ? q0 : q1;
    float qB = (hd0 == 0) ? q2 : q3;
    acc0 += xl[(size_t)s * HID + lane] * qA;
    acc1 += xl[(size_t)s * HID + 64 + lane] * qB;
  }
  float dA = ((hd0 == 0) ? s0 : s1) + 1e-16f;
  float dB = ((hd0 == 0) ? s2 : s3) + 1e-16f;
  float o0 = acc0 / dA + gbias[lane];
  float o1 = acc1 / dB + gbias[lane + 64];
  // layernorm over 128 channels (2 per lane) + relu + residual
  float mu = wave_sum64(o0 + o1) * (1.f / 128.f);
  float d0 = o0 - mu, d1 = o1 - mu;
  float var = wave_sum64(d0 * d0 + d1 * d1) * (1.f / 128.f);
  float r = rsqrtf(var + LN_EPS);
  float hn0 = fmaxf(d0 * r * lng[lane] + lnb[lane], 0.f);
  float hn1 = fmaxf(d1 * r * lng[lane + 64] + lnb[lane + 64], 0.f);
  h[(size_t)i * HID + lane] += hn0;
  h[(size_t)i * HID + 64 + lane] += hn1;
}

__device__ __forceinline__ int lower_bound_dev(const int* a, int n, int v) {
  int lo = 0, hi = n;
  while (lo < hi) {
    int mid = (lo + hi) >> 1;
    if (a[mid] < v) lo = mid + 1; else hi = mid;
  }
  return lo;
}

// per-batch mean pool (batch sorted) — deterministic, no atomics
__global__ __launch_bounds__(256) void pool_kernel(const float* __restrict__ h,
                                                   const int* __restrict__ batch,
                                                   float* __restrict__ pooled) {
  __shared__ float red[256];
  int b = blockIdx.x, tid = threadIdx.x;
  int start = lower_bound_dev(batch, N_NODES, b);
  int end = lower_bound_dev(batch, N_NODES, b + 1);
  int c = tid & 127, g = tid >> 7;
  float acc = 0.f;
  for (int n = start + g; n < end; n += 2) acc += h[(size_t)n * HID + c];
  red[tid] = acc;
  __syncthreads();
  if (g == 0) {
    float tot = red[tid] + red[tid + 128];
    float cntf = fmaxf((float)(end - start), 1.f);
    pooled[b * HID + c] = tot / cntf;
  }
}

// C[M,Nc] = act(A[M,K] @ W[Nc,K].T + bias); grid (ceil(Nc/64), ceil(M/4)), 256 thr
__global__ __launch_bounds__(256) void lin_kernel(const float* __restrict__ A, int lda,
                                                  const float* __restrict__ W,
                                                  const float* __restrict__ bias,
                                                  float* __restrict__ C, int ldc,
                                                  int M, int Nc, int K, int doRelu) {
  int c = blockIdx.x * 64 + (threadIdx.x & 63);
  int m = blockIdx.y * 4 + (threadIdx.x >> 6);
  if (c >= Nc || m >= M) return;
  const float4* a4 = (const float4*)(A + (size_t)m * lda);
  const float4* w4 = (const float4*)(W + (size_t)c * K);
  float acc = bias[c];
  for (int k = 0; k < (K >> 2); ++k) {
    float4 av = a4[k], wv = w4[k];
    acc += av.x * wv.x + av.y * wv.y + av.z * wv.z + av.w * wv.w;
  }
  if (doRelu) acc = fmaxf(acc, 0.f);
  C[(size_t)m * ldc + c] = acc;
}

__global__ __launch_bounds__(256) void concat_kernel(const float* __restrict__ seqh,
                                                     const float* __restrict__ strh,
                                                     float* __restrict__ comb) {
  int m = blockIdx.x, c = threadIdx.x;  // 256 threads
  comb[m * 1024 + 512 + c] = seqh[m * 256 + c];
  comb[m * 1024 + 768 + c] = strh[m * 256 + c];
}

extern "C" void kernel_launch(void* const* d_in, const int* in_sizes, int n_in,
                              void* d_out, int out_size, void* d_ws, size_t ws_size,
                              hipStream_t stream) {
  const float* seq_emb = (const float*)d_in[0];
  const float* x       = (const float*)d_in[1];
  const int* eidx      = (const int*)d_in[2];
  const int* batch     = (const int*)d_in[3];
  const float* ne_W = (const float*)d_in[4];
  const float* ne_b = (const float*)d_in[5];
  const float* gat_W = (const float*)d_in[6];
  const float* gat_asrc = (const float*)d_in[7];
  const float* gat_adst = (const float*)d_in[8];
  const float* gat_b = (const float*)d_in[9];
  const float* ln_g = (const float*)d_in[10];
  const float* ln_b = (const float*)d_in[11];
  const float* op1_W = (const float*)d_in[12];
  const float* op1_b = (const float*)d_in[13];
  const float* op2_W = (const float*)d_in[14];
  const float* op2_b = (const float*)d_in[15];
  const float* sp_W = (const float*)d_in[16];
  const float* sp_b = (const float*)d_in[17];
  const float* stp_W = (const float*)d_in[18];
  const float* stp_b = (const float*)d_in[19];
  const float* a1_Wi = (const float*)d_in[20];
  const float* a1_bi = (const float*)d_in[21];
  const float* a1_Wo = (const float*)d_in[22];
  const float* a1_bo = (const float*)d_in[23];
  const float* a2_Wi = (const float*)d_in[24];
  const float* a2_bi = (const float*)d_in[25];
  const float* a2_Wo = (const float*)d_in[26];
  const float* a2_bo = (const float*)d_in[27];
  const float* p1_W = (const float*)d_in[28];
  const float* p1_b = (const float*)d_in[29];
  const float* p2_W = (const float*)d_in[30];
  const float* p2_b = (const float*)d_in[31];
  const float* p3_W = (const float*)d_in[32];
  const float* p3_b = (const float*)d_in[33];

  const int E = in_sizes[2] / 2;
  const int* e_src = eidx;
  const int* e_dst = eidx + E;

  char* p = (char*)d_ws;
  auto alloc = [&](size_t bytes) -> void* {
    void* r = p;
    p += (bytes + 255) & ~(size_t)255;
    return r;
  };
  float* h    = (float*)alloc(sizeof(float) * (size_t)N_NODES * HID);
  float* xl   = (float*)alloc(sizeof(float) * (size_t)N_NODES * HID);
  float* esrc = (float*)alloc(sizeof(float) * (size_t)N_NODES * 4);
  float* edst = (float*)alloc(sizeof(float) * (size_t)N_NODES * 4);
  int* cnt    = (int*)alloc(sizeof(int) * N_NODES);
  int* cur    = (int*)alloc(sizeof(int) * N_NODES);
  int* off    = (int*)alloc(sizeof(int) * (N_NODES + 1));
  int* eadj   = (int*)alloc(sizeof(int) * (size_t)E);
  float* pooled = (float*)alloc(sizeof(float) * B_GRAPHS * HID);
  float* t1   = (float*)alloc(sizeof(float) * B_GRAPHS * HID);
  float* semb = (float*)alloc(sizeof(float) * B_GRAPHS * HID);
  float* seqh = (float*)alloc(sizeof(float) * B_GRAPHS * HD);
  float* strh = (float*)alloc(sizeof(float) * B_GRAPHS * HD);
  float* vbuf = (float*)alloc(sizeof(float) * B_GRAPHS * HD);
  float* comb = (float*)alloc(sizeof(float) * B_GRAPHS * 4 * HD);
  float* z1   = (float*)alloc(sizeof(float) * B_GRAPHS * HD);
  float* z2   = (float*)alloc(sizeof(float) * B_GRAPHS * (HD / 2));

  hipMemsetAsync(cnt, 0, sizeof(int) * N_NODES, stream);
  hipMemsetAsync(cur, 0, sizeof(int) * N_NODES, stream);

  ne_kernel<<<N_NODES * HID / 256, 256, 0, stream>>>(x, ne_W, ne_b, h);
  hist_kernel<<<(E + 255) / 256, 256, 0, stream>>>(e_dst, cnt, E);
  exscan_kernel<<<1, 1024, 0, stream>>>(cnt, off, N_NODES, E);
  scatter_kernel<<<(E + 255) / 256, 256, 0, stream>>>(e_src, e_dst, off, cur, eadj, E);

  for (int l = 0; l < L_LAYERS; ++l) {
    gat_xl_kernel<<<N_NODES / 16, 256, 0, stream>>>(
        h, gat_W + (size_t)l * HID * HID, gat_asrc + l * HID, gat_adst + l * HID,
        xl, esrc, edst);
    gat_agg_kernel<<<N_NODES / 4, 256, 0, stream>>>(
        xl, esrc, edst, off, eadj, gat_b + l * HID, ln_g + l * HID, ln_b + l * HID, h);
  }
  pool_kernel<<<B_GRAPHS, 256, 0, stream>>>(h, batch, pooled);

  dim3 blk(256);
  auto lgrid = [](int Nc) { return dim3((unsigned)((Nc + 63) / 64), (unsigned)(B_GRAPHS / 4)); };
  // struct_emb = relu(pooled@op1.T+b) @ op2.T + b
  lin_kernel<<<lgrid(HID), blk, 0, stream>>>(pooled, HID, op1_W, op1_b, t1, HID, B_GRAPHS, HID, HID, 1);
  lin_kernel<<<lgrid(HID), blk, 0, stream>>>(t1, HID, op2_W, op2_b, semb, HID, B_GRAPHS, HID, HID, 0);
  // seq_h, struct_h
  lin_kernel<<<lgrid(HD), blk, 0, stream>>>(seq_emb, SEQ_LEN, sp_W, sp_b, seqh, HD, B_GRAPHS, HD, SEQ_LEN, 0);
  lin_kernel<<<lgrid(HD), blk, 0, stream>>>(semb, HID, stp_W, stp_b, strh, HD, B_GRAPHS, HD, HID, 0);
  // MHA degenerates (seq len 1 => softmax == 1): att = (kv @ Wv.T + bv) @ Wo.T + bo
  lin_kernel<<<lgrid(HD), blk, 0, stream>>>(strh, HD, a1_Wi + 2 * HD * HD, a1_bi + 2 * HD, vbuf, HD, B_GRAPHS, HD, HD, 0);
  lin_kernel<<<lgrid(HD), blk, 0, stream>>>(vbuf, HD, a1_Wo, a1_bo, comb + 0, 4 * HD, B_GRAPHS, HD, HD, 0);
  lin_kernel<<<lgrid(HD), blk, 0, stream>>>(seqh, HD, a2_Wi + 2 * HD * HD, a2_bi + 2 * HD, vbuf, HD, B_GRAPHS, HD, HD, 0);
  lin_kernel<<<lgrid(HD), blk, 0, stream>>>(vbuf, HD, a2_Wo, a2_bo, comb + HD, 4 * HD, B_GRAPHS, HD, HD, 0);
  concat_kernel<<<B_GRAPHS, 256, 0, stream>>>(seqh, strh, comb);
  // final MLP
  lin_kernel<<<lgrid(HD), blk, 0, stream>>>(comb, 4 * HD, p1_W, p1_b, z1, HD, B_GRAPHS, HD, 4 * HD, 1);
  lin_kernel<<<lgrid(HD / 2), blk, 0, stream>>>(z1, HD, p2_W, p2_b, z2, HD / 2, B_GRAPHS, HD / 2, HD, 1);
  lin_kernel<<<lgrid(1), blk, 0, stream>>>(z2, HD / 2, p3_W, p3_b, (float*)d_out, 1, B_GRAPHS, 1, HD / 2, 0);
}

// Round 2
// 1044.634 us; speedup vs baseline: 2.0585x; 2.0585x over previous
//
#include <hip/hip_runtime.h>
#include <hip/hip_bf16.h>

#define N_NODES 100000
#define NFEAT 9
#define HID 128
#define B_GRAPHS 64
#define SEQ_LEN 768
#define HD 256
#define L_LAYERS 4
#define LN_EPS 1e-5f

__device__ __forceinline__ float lrelu(float v) { return v > 0.f ? v : 0.2f * v; }

__device__ __forceinline__ float wave_sum64(float x) {
#pragma unroll
  for (int o = 32; o >= 1; o >>= 1) x += __shfl_xor(x, o, 64);
  return x;
}

// h = relu(x @ ne_W.T + ne_b); thread per (node, col)
__global__ __launch_bounds__(256) void ne_kernel(const float* __restrict__ x,
                                                 const float* __restrict__ W,
                                                 const float* __restrict__ b,
                                                 float* __restrict__ h) {
  int idx = blockIdx.x * 256 + threadIdx.x;
  int n = idx >> 7, c = idx & 127;
  const float* xr = x + n * NFEAT;
  const float* wr = W + c * NFEAT;
  float acc = b[c];
#pragma unroll
  for (int k = 0; k < NFEAT; ++k) acc += xr[k] * wr[k];
  h[idx] = fmaxf(acc, 0.f);
}

__global__ __launch_bounds__(256) void hist_kernel(const int* __restrict__ dst,
                                                   int* __restrict__ cnt, int E) {
  int i = blockIdx.x * 256 + threadIdx.x;
  if (i < E) atomicAdd(&cnt[dst[i]], 1);
}

// hierarchical exclusive scan: scan1 (per-1024-block) -> scan2 (block sums) -> scan3 (add)
__global__ __launch_bounds__(1024) void scan1_kernel(const int* __restrict__ cnt,
                                                     int* __restrict__ off,
                                                     int* __restrict__ bsum, int n) {
  __shared__ int ws[16];
  __shared__ int wx[16];
  int tid = threadIdx.x, lane = tid & 63, w = tid >> 6;
  int i = blockIdx.x * 1024 + tid;
  int v = (i < n) ? cnt[i] : 0;
  int x = v;
#pragma unroll
  for (int o = 1; o < 64; o <<= 1) {
    int t = __shfl_up(x, o, 64);
    if (lane >= o) x += t;
  }
  if (lane == 63) ws[w] = x;
  __syncthreads();
  if (tid == 0) {
    int r = 0;
#pragma unroll
    for (int j = 0; j < 16; ++j) { int t = ws[j]; wx[j] = r; r += t; }
    bsum[blockIdx.x] = r;
  }
  __syncthreads();
  if (i < n) off[i] = wx[w] + x - v;
}

__global__ void scan2_kernel(int* __restrict__ bsum, int nb) {
  int lane = threadIdx.x;  // 64 threads, nb <= 128
  int i0 = lane * 2, i1 = i0 + 1;
  int a = (i0 < nb) ? bsum[i0] : 0;
  int b = (i1 < nb) ? bsum[i1] : 0;
  int s = a + b, x = s;
#pragma unroll
  for (int o = 1; o < 64; o <<= 1) {
    int t = __shfl_up(x, o, 64);
    if (lane >= o) x += t;
  }
  int excl = x - s;
  if (i0 < nb) bsum[i0] = excl;
  if (i1 < nb) bsum[i1] = excl + a;
}

__global__ __launch_bounds__(256) void scan3_kernel(const int* __restrict__ bsum,
                                                    int* __restrict__ off, int n, int total) {
  int i = blockIdx.x * 256 + threadIdx.x;
  if (i < n) off[i] += bsum[i >> 10];
  else if (i == n) off[i] = total;
}

__global__ __launch_bounds__(256) void scatter_kernel(const int* __restrict__ src,
                                                      const int* __restrict__ dst,
                                                      const int* __restrict__ off,
                                                      int* __restrict__ cur,
                                                      int* __restrict__ eadj, int E) {
  int i = blockIdx.x * 256 + threadIdx.x;
  if (i < E) {
    int d = dst[i];
    int pos = atomicAdd(&cur[d], 1);
    eadj[off[d] + pos] = src[i];
  }
}

// xl = h @ W.T : 128x128 output tile per block, 8x8 per thread, K chunked by 32.
// LDS transposed [kk][row] with stride 132 (16B-aligned, <=2-way bank alias).
__global__ __launch_bounds__(256) void gat_xl_kernel(const float* __restrict__ h,
                                                     const float* __restrict__ W,
                                                     const float* __restrict__ asrc,
                                                     const float* __restrict__ adst,
                                                     float* __restrict__ xl,
                                                     float* __restrict__ esrc,
                                                     float* __restrict__ edst) {
  __shared__ float As[32][132];
  __shared__ float Ws[32][132];
  const int tid = threadIdx.x;
  const int base = blockIdx.x * 128;
  const int lane = tid & 63;
  const int wv = tid >> 6;
  // wave-level 2x2 quadrants: 8x8 threads per wave
  const int r0 = (wv >> 1) * 64 + (lane >> 3) * 8;
  const int c0 = (wv & 1) * 64 + (lane & 7) * 8;

  float acc[8][8];
#pragma unroll
  for (int i = 0; i < 8; ++i)
#pragma unroll
    for (int j = 0; j < 8; ++j) acc[i][j] = 0.f;

  for (int k0 = 0; k0 < 128; k0 += 32) {
#pragma unroll
    for (int t = 0; t < 4; ++t) {
      int f4 = tid + t * 256;
      int row = f4 >> 3;
      int kko = (f4 & 7) << 2;
      int gn = base + row;
      if (gn >= N_NODES) gn = N_NODES - 1;
      float4 av = *(const float4*)(h + (size_t)gn * HID + k0 + kko);
      As[kko + 0][row] = av.x;
      As[kko + 1][row] = av.y;
      As[kko + 2][row] = av.z;
      As[kko + 3][row] = av.w;
      float4 wv4 = *(const float4*)(W + (size_t)row * HID + k0 + kko);
      Ws[kko + 0][row] = wv4.x;
      Ws[kko + 1][row] = wv4.y;
      Ws[kko + 2][row] = wv4.z;
      Ws[kko + 3][row] = wv4.w;
    }
    __syncthreads();
#pragma unroll 8
    for (int kk = 0; kk < 32; ++kk) {
      float4 a0 = *(const float4*)&As[kk][r0];
      float4 a1 = *(const float4*)&As[kk][r0 + 4];
      float4 w0 = *(const float4*)&Ws[kk][c0];
      float4 w1 = *(const float4*)&Ws[kk][c0 + 4];
      float a[8] = {a0.x, a0.y, a0.z, a0.w, a1.x, a1.y, a1.z, a1.w};
      float w[8] = {w0.x, w0.y, w0.z, w0.w, w1.x, w1.y, w1.z, w1.w};
#pragma unroll
      for (int i = 0; i < 8; ++i)
#pragma unroll
        for (int j = 0; j < 8; ++j) acc[i][j] += a[i] * w[j];
    }
    __syncthreads();
  }

  float asv[8], adv[8];
#pragma unroll
  for (int j = 0; j < 8; ++j) {
    asv[j] = asrc[c0 + j];
    adv[j] = adst[c0 + j];
  }
  const int head = c0 >> 5;
  const int tnw = lane & 7;
#pragma unroll
  for (int i = 0; i < 8; ++i) {
    int node = base + r0 + i;
    bool ok = node < N_NODES;
    if (ok) {
      *(float4*)(xl + (size_t)node * HID + c0) =
          make_float4(acc[i][0], acc[i][1], acc[i][2], acc[i][3]);
      *(float4*)(xl + (size_t)node * HID + c0 + 4) =
          make_float4(acc[i][4], acc[i][5], acc[i][6], acc[i][7]);
    }
    float ps = 0.f, pd = 0.f;
#pragma unroll
    for (int j = 0; j < 8; ++j) {
      ps += acc[i][j] * asv[j];
      pd += acc[i][j] * adv[j];
    }
    ps += __shfl_xor(ps, 1, 64);
    ps += __shfl_xor(ps, 2, 64);
    pd += __shfl_xor(pd, 1, 64);
    pd += __shfl_xor(pd, 2, 64);
    if (ok && (tnw & 3) == 0) {
      esrc[node * 4 + head] = ps;
      edst[node * 4 + head] = pd;
    }
  }
}

// single-pass softmax aggregation (no max subtraction; |logits| ~ O(1), exp safe)
// + bias + LN + relu + residual. Wave per node.
__global__ __launch_bounds__(256) void gat_agg_kernel(const float* __restrict__ xl,
                                                      const float* __restrict__ esrc,
                                                      const float* __restrict__ edst,
                                                      const int* __restrict__ off,
                                                      const int* __restrict__ eadj,
                                                      const float* __restrict__ gbias,
                                                      const float* __restrict__ lng,
                                                      const float* __restrict__ lnb,
                                                      float* __restrict__ h) {
  const int tid = threadIdx.x;
  const int lane = tid & 63;
  const int i = blockIdx.x * 4 + (tid >> 6);
  const int hd0 = lane >> 5;

  const float4 ed = *(const float4*)(edst + (size_t)i * 4);
  const float4 e0 = *(const float4*)(esrc + (size_t)i * 4);
  float w0 = __expf(lrelu(e0.x + ed.x));
  float w1 = __expf(lrelu(e0.y + ed.y));
  float w2 = __expf(lrelu(e0.z + ed.z));
  float w3 = __expf(lrelu(e0.w + ed.w));
  float s0 = w0, s1 = w1, s2 = w2, s3 = w3;
  const float* xr = xl + lane;
  float accA = xr[(size_t)i * HID] * (hd0 == 0 ? w0 : w1);
  float accB = xr[(size_t)i * HID + 64] * (hd0 == 0 ? w2 : w3);
  const int beg = off[i], end = off[i + 1];
  int sN = (beg < end) ? eadj[beg] : 0;
  float4 esN = (beg < end) ? *(const float4*)(esrc + (size_t)sN * 4) : e0;
  for (int j = beg; j < end; ++j) {
    const int sc = sN;
    const float4 es = esN;
    if (j + 1 < end) {
      sN = eadj[j + 1];
      esN = *(const float4*)(esrc + (size_t)sN * 4);
    }
    float xA = xr[(size_t)sc * HID];
    float xB = xr[(size_t)sc * HID + 64];
    float q0 = __expf(lrelu(es.x + ed.x));
    float q1 = __expf(lrelu(es.y + ed.y));
    float q2 = __expf(lrelu(es.z + ed.z));
    float q3 = __expf(lrelu(es.w + ed.w));
    s0 += q0; s1 += q1; s2 += q2; s3 += q3;
    accA += xA * (hd0 == 0 ? q0 : q1);
    accB += xB * (hd0 == 0 ? q2 : q3);
  }
  float dA = (hd0 == 0 ? s0 : s1) + 1e-16f;
  float dB = (hd0 == 0 ? s2 : s3) + 1e-16f;
  float o0 = accA / dA + gbias[lane];
  float o1 = accB / dB + gbias[lane + 64];
  float mu = wave_sum64(o0 + o1) * (1.f / 128.f);
  float d0 = o0 - mu, d1 = o1 - mu;
  float var = wave_sum64(d0 * d0 + d1 * d1) * (1.f / 128.f);
  float r = rsqrtf(var + LN_EPS);
  float hn0 = fmaxf(d0 * r * lng[lane] + lnb[lane], 0.f);
  float hn1 = fmaxf(d1 * r * lng[lane + 64] + lnb[lane + 64], 0.f);
  h[(size_t)i * HID + lane] += hn0;
  h[(size_t)i * HID + 64 + lane] += hn1;
}

__device__ __forceinline__ int lower_bound_dev(const int* a, int n, int v) {
  int lo = 0, hi = n;
  while (lo < hi) {
    int mid = (lo + hi) >> 1;
    if (a[mid] < v) lo = mid + 1; else hi = mid;
  }
  return lo;
}

// per-batch mean pool; grid (B, 4): 32-col slices, 8 row strides per block
__global__ __launch_bounds__(256) void pool_kernel(const float* __restrict__ h,
                                                   const int* __restrict__ batch,
                                                   float* __restrict__ pooled) {
  __shared__ float red[256];
  int b = blockIdx.x, tid = threadIdx.x;
  int start = lower_bound_dev(batch, N_NODES, b);
  int end = lower_bound_dev(batch, N_NODES, b + 1);
  int cl = tid & 31, g = tid >> 5;
  int c = cl + blockIdx.y * 32;
  float acc = 0.f;
  for (int n = start + g; n < end; n += 8) acc += h[(size_t)n * HID + c];
  red[tid] = acc;
  __syncthreads();
  if (g == 0) {
    float tot = 0.f;
#pragma unroll
    for (int k = 0; k < 8; ++k) tot += red[cl + 32 * k];
    float cntf = fmaxf((float)(end - start), 1.f);
    pooled[b * HID + c] = tot / cntf;
  }
}

// C[M,Nc] = act(A[M,K] @ W[Nc,K].T + bias); grid (ceil(Nc/64), ceil(M/4)), 256 thr
__global__ __launch_bounds__(256) void lin_kernel(const float* __restrict__ A, int lda,
                                                  const float* __restrict__ W,
                                                  const float* __restrict__ bias,
                                                  float* __restrict__ C, int ldc,
                                                  int M, int Nc, int K, int doRelu) {
  int c = blockIdx.x * 64 + (threadIdx.x & 63);
  int m = blockIdx.y * 4 + (threadIdx.x >> 6);
  if (c >= Nc || m >= M) return;
  const float4* a4 = (const float4*)(A + (size_t)m * lda);
  const float4* w4 = (const float4*)(W + (size_t)c * K);
  float acc = bias[c];
  for (int k = 0; k < (K >> 2); ++k) {
    float4 av = a4[k], wv = w4[k];
    acc += av.x * wv.x + av.y * wv.y + av.z * wv.z + av.w * wv.w;
  }
  if (doRelu) acc = fmaxf(acc, 0.f);
  C[(size_t)m * ldc + c] = acc;
}

__global__ __launch_bounds__(256) void concat_kernel(const float* __restrict__ seqh,
                                                     const float* __restrict__ strh,
                                                     float* __restrict__ comb) {
  int m = blockIdx.x, c = threadIdx.x;
  comb[m * 1024 + 512 + c] = seqh[m * 256 + c];
  comb[m * 1024 + 768 + c] = strh[m * 256 + c];
}

extern "C" void kernel_launch(void* const* d_in, const int* in_sizes, int n_in,
                              void* d_out, int out_size, void* d_ws, size_t ws_size,
                              hipStream_t stream) {
  const float* seq_emb = (const float*)d_in[0];
  const float* x       = (const float*)d_in[1];
  const int* eidx      = (const int*)d_in[2];
  const int* batch     = (const int*)d_in[3];
  const float* ne_W = (const float*)d_in[4];
  const float* ne_b = (const float*)d_in[5];
  const float* gat_W = (const float*)d_in[6];
  const float* gat_asrc = (const float*)d_in[7];
  const float* gat_adst = (const float*)d_in[8];
  const float* gat_b = (const float*)d_in[9];
  const float* ln_g = (const float*)d_in[10];
  const float* ln_b = (const float*)d_in[11];
  const float* op1_W = (const float*)d_in[12];
  const float* op1_b = (const float*)d_in[13];
  const float* op2_W = (const float*)d_in[14];
  const float* op2_b = (const float*)d_in[15];
  const float* sp_W = (const float*)d_in[16];
  const float* sp_b = (const float*)d_in[17];
  const float* stp_W = (const float*)d_in[18];
  const float* stp_b = (const float*)d_in[19];
  const float* a1_Wi = (const float*)d_in[20];
  const float* a1_bi = (const float*)d_in[21];
  const float* a1_Wo = (const float*)d_in[22];
  const float* a1_bo = (const float*)d_in[23];
  const float* a2_Wi = (const float*)d_in[24];
  const float* a2_bi = (const float*)d_in[25];
  const float* a2_Wo = (const float*)d_in[26];
  const float* a2_bo = (const float*)d_in[27];
  const float* p1_W = (const float*)d_in[28];
  const float* p1_b = (const float*)d_in[29];
  const float* p2_W = (const float*)d_in[30];
  const float* p2_b = (const float*)d_in[31];
  const float* p3_W = (const float*)d_in[32];
  const float* p3_b = (const float*)d_in[33];

  const int E = in_sizes[2] / 2;
  const int* e_src = eidx;
  const int* e_dst = eidx + E;

  char* p = (char*)d_ws;
  auto alloc = [&](size_t bytes) -> void* {
    void* r = p;
    p += (bytes + 255) & ~(size_t)255;
    return r;
  };
  float* h    = (float*)alloc(sizeof(float) * (size_t)N_NODES * HID);
  float* xl   = (float*)alloc(sizeof(float) * (size_t)N_NODES * HID);
  float* esrc = (float*)alloc(sizeof(float) * (size_t)N_NODES * 4);
  float* edst = (float*)alloc(sizeof(float) * (size_t)N_NODES * 4);
  int* cnt    = (int*)alloc(sizeof(int) * N_NODES);
  int* cur    = (int*)alloc(sizeof(int) * N_NODES);
  int* off    = (int*)alloc(sizeof(int) * (N_NODES + 1));
  int* eadj   = (int*)alloc(sizeof(int) * (size_t)E);
  int* bsum   = (int*)alloc(sizeof(int) * 128);
  float* pooled = (float*)alloc(sizeof(float) * B_GRAPHS * HID);
  float* t1   = (float*)alloc(sizeof(float) * B_GRAPHS * HID);
  float* semb = (float*)alloc(sizeof(float) * B_GRAPHS * HID);
  float* seqh = (float*)alloc(sizeof(float) * B_GRAPHS * HD);
  float* strh = (float*)alloc(sizeof(float) * B_GRAPHS * HD);
  float* vbuf = (float*)alloc(sizeof(float) * B_GRAPHS * HD);
  float* comb = (float*)alloc(sizeof(float) * B_GRAPHS * 4 * HD);
  float* z1   = (float*)alloc(sizeof(float) * B_GRAPHS * HD);
  float* z2   = (float*)alloc(sizeof(float) * B_GRAPHS * (HD / 2));

  hipMemsetAsync(cnt, 0, sizeof(int) * N_NODES, stream);
  hipMemsetAsync(cur, 0, sizeof(int) * N_NODES, stream);

  const int SCAN_BLKS = (N_NODES + 1023) / 1024;  // 98
  ne_kernel<<<N_NODES * HID / 256, 256, 0, stream>>>(x, ne_W, ne_b, h);
  hist_kernel<<<(E + 255) / 256, 256, 0, stream>>>(e_dst, cnt, E);
  scan1_kernel<<<SCAN_BLKS, 1024, 0, stream>>>(cnt, off, bsum, N_NODES);
  scan2_kernel<<<1, 64, 0, stream>>>(bsum, SCAN_BLKS);
  scan3_kernel<<<(N_NODES + 256) / 256, 256, 0, stream>>>(bsum, off, N_NODES, E);
  scatter_kernel<<<(E + 255) / 256, 256, 0, stream>>>(e_src, e_dst, off, cur, eadj, E);

  for (int l = 0; l < L_LAYERS; ++l) {
    gat_xl_kernel<<<(N_NODES + 127) / 128, 256, 0, stream>>>(
        h, gat_W + (size_t)l * HID * HID, gat_asrc + l * HID, gat_adst + l * HID,
        xl, esrc, edst);
    gat_agg_kernel<<<N_NODES / 4, 256, 0, stream>>>(
        xl, esrc, edst, off, eadj, gat_b + l * HID, ln_g + l * HID, ln_b + l * HID, h);
  }
  pool_kernel<<<dim3(B_GRAPHS, 4), 256, 0, stream>>>(h, batch, pooled);

  dim3 blk(256);
  auto lgrid = [](int Nc) { return dim3((unsigned)((Nc + 63) / 64), (unsigned)(B_GRAPHS / 4)); };
  lin_kernel<<<lgrid(HID), blk, 0, stream>>>(pooled, HID, op1_W, op1_b, t1, HID, B_GRAPHS, HID, HID, 1);
  lin_kernel<<<lgrid(HID), blk, 0, stream>>>(t1, HID, op2_W, op2_b, semb, HID, B_GRAPHS, HID, HID, 0);
  lin_kernel<<<lgrid(HD), blk, 0, stream>>>(seq_emb, SEQ_LEN, sp_W, sp_b, seqh, HD, B_GRAPHS, HD, SEQ_LEN, 0);
  lin_kernel<<<lgrid(HD), blk, 0, stream>>>(semb, HID, stp_W, stp_b, strh, HD, B_GRAPHS, HD, HID, 0);
  lin_kernel<<<lgrid(HD), blk, 0, stream>>>(strh, HD, a1_Wi + 2 * HD * HD, a1_bi + 2 * HD, vbuf, HD, B_GRAPHS, HD, HD, 0);
  lin_kernel<<<lgrid(HD), blk, 0, stream>>>(vbuf, HD, a1_Wo, a1_bo, comb + 0, 4 * HD, B_GRAPHS, HD, HD, 0);
  lin_kernel<<<lgrid(HD), blk, 0, stream>>>(seqh, HD, a2_Wi + 2 * HD * HD, a2_bi + 2 * HD, vbuf, HD, B_GRAPHS, HD, HD, 0);
  lin_kernel<<<lgrid(HD), blk, 0, stream>>>(vbuf, HD, a2_Wo, a2_bo, comb + HD, 4 * HD, B_GRAPHS, HD, HD, 0);
  concat_kernel<<<B_GRAPHS, 256, 0, stream>>>(seqh, strh, comb);
  lin_kernel<<<lgrid(HD), blk, 0, stream>>>(comb, 4 * HD, p1_W, p1_b, z1, HD, B_GRAPHS, HD, 4 * HD, 1);
  lin_kernel<<<lgrid(HD / 2), blk, 0, stream>>>(z1, HD, p2_W, p2_b, z2, HD / 2, B_GRAPHS, HD / 2, HD, 1);
  lin_kernel<<<lgrid(1), blk, 0, stream>>>(z2, HD / 2, p3_W, p3_b, (float*)d_out, 1, B_GRAPHS, 1, HD / 2, 0);
}

// Round 3
// 862.975 us; speedup vs baseline: 2.4918x; 1.2105x over previous
//
#include <hip/hip_runtime.h>
#include <hip/hip_bf16.h>

#define N_NODES 100000
#define NFEAT 9
#define HID 128
#define B_GRAPHS 64
#define SEQ_LEN 768
#define HD 256
#define L_LAYERS 4
#define LN_EPS 1e-5f

__device__ __forceinline__ float lrelu(float v) { return v > 0.f ? v : 0.2f * v; }

__device__ __forceinline__ float wave_sum64(float x) {
#pragma unroll
  for (int o = 32; o >= 1; o >>= 1) x += __shfl_xor(x, o, 64);
  return x;
}

// h = relu(x @ ne_W.T + ne_b); thread per (node, col)
__global__ __launch_bounds__(256) void ne_kernel(const float* __restrict__ x,
                                                 const float* __restrict__ W,
                                                 const float* __restrict__ b,
                                                 float* __restrict__ h) {
  int idx = blockIdx.x * 256 + threadIdx.x;
  int n = idx >> 7, c = idx & 127;
  const float* xr = x + n * NFEAT;
  const float* wr = W + c * NFEAT;
  float acc = b[c];
#pragma unroll
  for (int k = 0; k < NFEAT; ++k) acc += xr[k] * wr[k];
  h[idx] = fmaxf(acc, 0.f);
}

__global__ __launch_bounds__(256) void hist_kernel(const int* __restrict__ dst,
                                                   int* __restrict__ cnt, int E) {
  int i = blockIdx.x * 256 + threadIdx.x;
  if (i < E) atomicAdd(&cnt[dst[i]], 1);
}

// hierarchical exclusive scan
__global__ __launch_bounds__(1024) void scan1_kernel(const int* __restrict__ cnt,
                                                     int* __restrict__ off,
                                                     int* __restrict__ bsum, int n) {
  __shared__ int ws[16];
  __shared__ int wx[16];
  int tid = threadIdx.x, lane = tid & 63, w = tid >> 6;
  int i = blockIdx.x * 1024 + tid;
  int v = (i < n) ? cnt[i] : 0;
  int x = v;
#pragma unroll
  for (int o = 1; o < 64; o <<= 1) {
    int t = __shfl_up(x, o, 64);
    if (lane >= o) x += t;
  }
  if (lane == 63) ws[w] = x;
  __syncthreads();
  if (tid == 0) {
    int r = 0;
#pragma unroll
    for (int j = 0; j < 16; ++j) { int t = ws[j]; wx[j] = r; r += t; }
    bsum[blockIdx.x] = r;
  }
  __syncthreads();
  if (i < n) off[i] = wx[w] + x - v;
}

__global__ void scan2_kernel(int* __restrict__ bsum, int nb) {
  int lane = threadIdx.x;
  int i0 = lane * 2, i1 = i0 + 1;
  int a = (i0 < nb) ? bsum[i0] : 0;
  int b = (i1 < nb) ? bsum[i1] : 0;
  int s = a + b, x = s;
#pragma unroll
  for (int o = 1; o < 64; o <<= 1) {
    int t = __shfl_up(x, o, 64);
    if (lane >= o) x += t;
  }
  int excl = x - s;
  if (i0 < nb) bsum[i0] = excl;
  if (i1 < nb) bsum[i1] = excl + a;
}

__global__ __launch_bounds__(256) void scan3_kernel(const int* __restrict__ bsum,
                                                    int* __restrict__ off, int n, int total) {
  int i = blockIdx.x * 256 + threadIdx.x;
  if (i < n) off[i] += bsum[i >> 10];
  else if (i == n) off[i] = total;
}

__global__ __launch_bounds__(256) void scatter_kernel(const int* __restrict__ src,
                                                      const int* __restrict__ dst,
                                                      const int* __restrict__ off,
                                                      int* __restrict__ cur,
                                                      int* __restrict__ eadj, int E) {
  int i = blockIdx.x * 256 + threadIdx.x;
  if (i < E) {
    int d = dst[i];
    int pos = atomicAdd(&cur[d], 1);
    eadj[off[d] + pos] = src[i];
  }
}

// xl = h @ W.T : 128x128 tile per block, 8x8 per thread, K chunked by 32.
__global__ __launch_bounds__(256) void gat_xl_kernel(const float* __restrict__ h,
                                                     const float* __restrict__ W,
                                                     const float* __restrict__ asrc,
                                                     const float* __restrict__ adst,
                                                     float* __restrict__ xl,
                                                     float* __restrict__ esrc,
                                                     float* __restrict__ edst) {
  __shared__ float As[32][132];
  __shared__ float Ws[32][132];
  const int tid = threadIdx.x;
  const int base = blockIdx.x * 128;
  const int lane = tid & 63;
  const int wv = tid >> 6;
  const int r0 = (wv >> 1) * 64 + (lane >> 3) * 8;
  const int c0 = (wv & 1) * 64 + (lane & 7) * 8;

  float acc[8][8];
#pragma unroll
  for (int i = 0; i < 8; ++i)
#pragma unroll
    for (int j = 0; j < 8; ++j) acc[i][j] = 0.f;

  for (int k0 = 0; k0 < 128; k0 += 32) {
#pragma unroll
    for (int t = 0; t < 4; ++t) {
      int f4 = tid + t * 256;
      int row = f4 >> 3;
      int kko = (f4 & 7) << 2;
      int gn = base + row;
      if (gn >= N_NODES) gn = N_NODES - 1;
      float4 av = *(const float4*)(h + (size_t)gn * HID + k0 + kko);
      As[kko + 0][row] = av.x;
      As[kko + 1][row] = av.y;
      As[kko + 2][row] = av.z;
      As[kko + 3][row] = av.w;
      float4 wv4 = *(const float4*)(W + (size_t)row * HID + k0 + kko);
      Ws[kko + 0][row] = wv4.x;
      Ws[kko + 1][row] = wv4.y;
      Ws[kko + 2][row] = wv4.z;
      Ws[kko + 3][row] = wv4.w;
    }
    __syncthreads();
#pragma unroll 8
    for (int kk = 0; kk < 32; ++kk) {
      float4 a0 = *(const float4*)&As[kk][r0];
      float4 a1 = *(const float4*)&As[kk][r0 + 4];
      float4 w0 = *(const float4*)&Ws[kk][c0];
      float4 w1 = *(const float4*)&Ws[kk][c0 + 4];
      float a[8] = {a0.x, a0.y, a0.z, a0.w, a1.x, a1.y, a1.z, a1.w};
      float w[8] = {w0.x, w0.y, w0.z, w0.w, w1.x, w1.y, w1.z, w1.w};
#pragma unroll
      for (int i = 0; i < 8; ++i)
#pragma unroll
        for (int j = 0; j < 8; ++j) acc[i][j] += a[i] * w[j];
    }
    __syncthreads();
  }

  float asv[8], adv[8];
#pragma unroll
  for (int j = 0; j < 8; ++j) {
    asv[j] = asrc[c0 + j];
    adv[j] = adst[c0 + j];
  }
  const int head = c0 >> 5;
  const int tnw = lane & 7;
#pragma unroll
  for (int i = 0; i < 8; ++i) {
    int node = base + r0 + i;
    bool ok = node < N_NODES;
    if (ok) {
      *(float4*)(xl + (size_t)node * HID + c0) =
          make_float4(acc[i][0], acc[i][1], acc[i][2], acc[i][3]);
      *(float4*)(xl + (size_t)node * HID + c0 + 4) =
          make_float4(acc[i][4], acc[i][5], acc[i][6], acc[i][7]);
    }
    float ps = 0.f, pd = 0.f;
#pragma unroll
    for (int j = 0; j < 8; ++j) {
      ps += acc[i][j] * asv[j];
      pd += acc[i][j] * adv[j];
    }
    ps += __shfl_xor(ps, 1, 64);
    ps += __shfl_xor(ps, 2, 64);
    pd += __shfl_xor(pd, 1, 64);
    pd += __shfl_xor(pd, 2, 64);
    if (ok && (tnw & 3) == 0) {
      esrc[node * 4 + head] = ps;
      edst[node * 4 + head] = pd;
    }
  }
}

// single-pass softmax aggregation, 4-edge software pipeline. Wave per node.
__global__ __launch_bounds__(256) void gat_agg_kernel(const float* __restrict__ xl,
                                                      const float* __restrict__ esrc,
                                                      const float* __restrict__ edst,
                                                      const int* __restrict__ off,
                                                      const int* __restrict__ eadj,
                                                      const float* __restrict__ gbias,
                                                      const float* __restrict__ lng,
                                                      const float* __restrict__ lnb,
                                                      float* __restrict__ h) {
  const int tid = threadIdx.x;
  const int lane = tid & 63;
  const int i = blockIdx.x * 4 + (tid >> 6);
  const int hd0 = lane >> 5;

  const float4 ed = *(const float4*)(edst + (size_t)i * 4);
  const float4 e0 = *(const float4*)(esrc + (size_t)i * 4);
  float w0 = __expf(lrelu(e0.x + ed.x));
  float w1 = __expf(lrelu(e0.y + ed.y));
  float w2 = __expf(lrelu(e0.z + ed.z));
  float w3 = __expf(lrelu(e0.w + ed.w));
  float s0 = w0, s1 = w1, s2 = w2, s3 = w3;
  const float* xr = xl + lane;
  float accA = xr[i * HID] * (hd0 == 0 ? w0 : w1);
  float accB = xr[i * HID + 64] * (hd0 == 0 ? w2 : w3);
  const int beg = off[i], end = off[i + 1];
  int j = beg;
  for (; j + 4 <= end; j += 4) {
    const int sa = eadj[j + 0];
    const int sb = eadj[j + 1];
    const int sc = eadj[j + 2];
    const int sd = eadj[j + 3];
    const float4 Ea = *(const float4*)(esrc + (size_t)sa * 4);
    const float4 Eb = *(const float4*)(esrc + (size_t)sb * 4);
    const float4 Ec = *(const float4*)(esrc + (size_t)sc * 4);
    const float4 Ed = *(const float4*)(esrc + (size_t)sd * 4);
    const float xa0 = xr[sa * HID], xa1 = xr[sa * HID + 64];
    const float xb0 = xr[sb * HID], xb1 = xr[sb * HID + 64];
    const float xc0 = xr[sc * HID], xc1 = xr[sc * HID + 64];
    const float xd0 = xr[sd * HID], xd1 = xr[sd * HID + 64];
    float qa0 = __expf(lrelu(Ea.x + ed.x)), qa1 = __expf(lrelu(Ea.y + ed.y));
    float qa2 = __expf(lrelu(Ea.z + ed.z)), qa3 = __expf(lrelu(Ea.w + ed.w));
    float qb0 = __expf(lrelu(Eb.x + ed.x)), qb1 = __expf(lrelu(Eb.y + ed.y));
    float qb2 = __expf(lrelu(Eb.z + ed.z)), qb3 = __expf(lrelu(Eb.w + ed.w));
    float qc0 = __expf(lrelu(Ec.x + ed.x)), qc1 = __expf(lrelu(Ec.y + ed.y));
    float qc2 = __expf(lrelu(Ec.z + ed.z)), qc3 = __expf(lrelu(Ec.w + ed.w));
    float qd0 = __expf(lrelu(Ed.x + ed.x)), qd1 = __expf(lrelu(Ed.y + ed.y));
    float qd2 = __expf(lrelu(Ed.z + ed.z)), qd3 = __expf(lrelu(Ed.w + ed.w));
    s0 += qa0 + qb0 + qc0 + qd0;
    s1 += qa1 + qb1 + qc1 + qd1;
    s2 += qa2 + qb2 + qc2 + qd2;
    s3 += qa3 + qb3 + qc3 + qd3;
    accA += xa0 * (hd0 == 0 ? qa0 : qa1) + xb0 * (hd0 == 0 ? qb0 : qb1) +
            xc0 * (hd0 == 0 ? qc0 : qc1) + xd0 * (hd0 == 0 ? qd0 : qd1);
    accB += xa1 * (hd0 == 0 ? qa2 : qa3) + xb1 * (hd0 == 0 ? qb2 : qb3) +
            xc1 * (hd0 == 0 ? qc2 : qc3) + xd1 * (hd0 == 0 ? qd2 : qd3);
  }
  for (; j < end; ++j) {
    const int sc = eadj[j];
    const float4 es = *(const float4*)(esrc + (size_t)sc * 4);
    const float xA = xr[sc * HID];
    const float xB = xr[sc * HID + 64];
    float q0 = __expf(lrelu(es.x + ed.x));
    float q1 = __expf(lrelu(es.y + ed.y));
    float q2 = __expf(lrelu(es.z + ed.z));
    float q3 = __expf(lrelu(es.w + ed.w));
    s0 += q0; s1 += q1; s2 += q2; s3 += q3;
    accA += xA * (hd0 == 0 ? q0 : q1);
    accB += xB * (hd0 == 0 ? q2 : q3);
  }
  float dA = (hd0 == 0 ? s0 : s1) + 1e-16f;
  float dB = (hd0 == 0 ? s2 : s3) + 1e-16f;
  float o0 = accA / dA + gbias[lane];
  float o1 = accB / dB + gbias[lane + 64];
  float mu = wave_sum64(o0 + o1) * (1.f / 128.f);
  float d0 = o0 - mu, d1 = o1 - mu;
  float var = wave_sum64(d0 * d0 + d1 * d1) * (1.f / 128.f);
  float r = rsqrtf(var + LN_EPS);
  float hn0 = fmaxf(d0 * r * lng[lane] + lnb[lane], 0.f);
  float hn1 = fmaxf(d1 * r * lng[lane + 64] + lnb[lane + 64], 0.f);
  h[(size_t)i * HID + lane] += hn0;
  h[(size_t)i * HID + 64 + lane] += hn1;
}

__device__ __forceinline__ int lower_bound_dev(const int* a, int n, int v) {
  int lo = 0, hi = n;
  while (lo < hi) {
    int mid = (lo + hi) >> 1;
    if (a[mid] < v) lo = mid + 1; else hi = mid;
  }
  return lo;
}

// per-batch mean pool; grid (B, 4)
__global__ __launch_bounds__(256) void pool_kernel(const float* __restrict__ h,
                                                   const int* __restrict__ batch,
                                                   float* __restrict__ pooled) {
  __shared__ float red[256];
  int b = blockIdx.x, tid = threadIdx.x;
  int start = lower_bound_dev(batch, N_NODES, b);
  int end = lower_bound_dev(batch, N_NODES, b + 1);
  int cl = tid & 31, g = tid >> 5;
  int c = cl + blockIdx.y * 32;
  float acc = 0.f;
  for (int n = start + g; n < end; n += 8) acc += h[(size_t)n * HID + c];
  red[tid] = acc;
  __syncthreads();
  if (g == 0) {
    float tot = 0.f;
#pragma unroll
    for (int k = 0; k < 8; ++k) tot += red[cl + 32 * k];
    float cntf = fmaxf((float)(end - start), 1.f);
    pooled[b * HID + c] = tot / cntf;
  }
}

// dot of LDS vector s[0..K) with global row w[0..K)
__device__ __forceinline__ float dotK(const float* __restrict__ w, const float* s, int K) {
  float acc = 0.f;
  for (int k = 0; k < K; k += 4) {
    float4 wv = *(const float4*)(w + k);
    acc += wv.x * s[k] + wv.y * s[k + 1] + wv.z * s[k + 2] + wv.w * s[k + 3];
  }
  return acc;
}

// Entire post-pool head fused: one block per batch row m.
__global__ __launch_bounds__(256) void head_kernel(
    const float* __restrict__ pooled, const float* __restrict__ seq_emb,
    const float* __restrict__ op1_W, const float* __restrict__ op1_b,
    const float* __restrict__ op2_W, const float* __restrict__ op2_b,
    const float* __restrict__ sp_W, const float* __restrict__ sp_b,
    const float* __restrict__ stp_W, const float* __restrict__ stp_b,
    const float* __restrict__ a1_Wi, const float* __restrict__ a1_bi,
    const float* __restrict__ a1_Wo, const float* __restrict__ a1_bo,
    const float* __restrict__ a2_Wi, const float* __restrict__ a2_bi,
    const float* __restrict__ a2_Wo, const float* __restrict__ a2_bo,
    const float* __restrict__ p1_W, const float* __restrict__ p1_b,
    const float* __restrict__ p2_W, const float* __restrict__ p2_b,
    const float* __restrict__ p3_W, const float* __restrict__ p3_b,
    float* __restrict__ out) {
  const int m = blockIdx.x, tid = threadIdx.x;
  __shared__ float sSeq[SEQ_LEN];
  __shared__ float sPool[HID];
  __shared__ float sA[HD];     // t1 -> v1
  __shared__ float sB[HD];     // semb -> v2
  __shared__ float sSeqh[HD];
  __shared__ float sStrh[HD];
  __shared__ float sComb[4 * HD];
  __shared__ float sZ1[HD];
  __shared__ float sZ2[HD / 2];

  for (int k = tid; k < SEQ_LEN; k += 256) sSeq[k] = seq_emb[m * SEQ_LEN + k];
  if (tid < HID) sPool[tid] = pooled[m * HID + tid];
  __syncthreads();

  // S1: seqh (all threads) ; t1 (tid<128)
  {
    float v = dotK(sp_W + (size_t)tid * SEQ_LEN, sSeq, SEQ_LEN) + sp_b[tid];
    sSeqh[tid] = v;
    sComb[2 * HD + tid] = v;
  }
  if (tid < HID) sA[tid] = fmaxf(dotK(op1_W + tid * HID, sPool, HID) + op1_b[tid], 0.f);
  __syncthreads();

  // S2: semb
  if (tid < HID) sB[tid] = dotK(op2_W + tid * HID, sA, HID) + op2_b[tid];
  __syncthreads();

  // S3: strh ; v2 = seqh @ a2_Wv -> sZ1 (temp)
  {
    float v = dotK(stp_W + tid * HID, sB, HID) + stp_b[tid];
    sStrh[tid] = v;
    sComb[3 * HD + tid] = v;
  }
  sZ1[tid] = dotK(a2_Wi + 2 * HD * HD + (size_t)tid * HD, sSeqh, HD) + a2_bi[2 * HD + tid];
  __syncthreads();

  // S4: v1 = strh @ a1_Wv -> sA ; att2 = v2 @ a2_Wo -> comb[HD..2HD)
  sA[tid] = dotK(a1_Wi + 2 * HD * HD + (size_t)tid * HD, sStrh, HD) + a1_bi[2 * HD + tid];
  sComb[HD + tid] = dotK(a2_Wo + (size_t)tid * HD, sZ1, HD) + a2_bo[tid];
  __syncthreads();

  // S5: att1 = v1 @ a1_Wo -> comb[0..HD)
  sComb[tid] = dotK(a1_Wo + (size_t)tid * HD, sA, HD) + a1_bo[tid];
  __syncthreads();

  // S6: z1 = relu(comb @ p1_W.T + b)
  sZ1[tid] = fmaxf(dotK(p1_W + (size_t)tid * 4 * HD, sComb, 4 * HD) + p1_b[tid], 0.f);
  __syncthreads();

  // S7: z2
  if (tid < HD / 2) sZ2[tid] = fmaxf(dotK(p2_W + tid * HD, sZ1, HD) + p2_b[tid], 0.f);
  __syncthreads();

  // S8: out
  if (tid < 64) {
    float part = sZ2[tid] * p3_W[tid] + sZ2[tid + 64] * p3_W[tid + 64];
    part = wave_sum64(part);
    if (tid == 0) out[m] = part + p3_b[0];
  }
}

extern "C" void kernel_launch(void* const* d_in, const int* in_sizes, int n_in,
                              void* d_out, int out_size, void* d_ws, size_t ws_size,
                              hipStream_t stream) {
  const float* seq_emb = (const float*)d_in[0];
  const float* x       = (const float*)d_in[1];
  const int* eidx      = (const int*)d_in[2];
  const int* batch     = (const int*)d_in[3];
  const float* ne_W = (const float*)d_in[4];
  const float* ne_b = (const float*)d_in[5];
  const float* gat_W = (const float*)d_in[6];
  const float* gat_asrc = (const float*)d_in[7];
  const float* gat_adst = (const float*)d_in[8];
  const float* gat_b = (const float*)d_in[9];
  const float* ln_g = (const float*)d_in[10];
  const float* ln_b = (const float*)d_in[11];
  const float* op1_W = (const float*)d_in[12];
  const float* op1_b = (const float*)d_in[13];
  const float* op2_W = (const float*)d_in[14];
  const float* op2_b = (const float*)d_in[15];
  const float* sp_W = (const float*)d_in[16];
  const float* sp_b = (const float*)d_in[17];
  const float* stp_W = (const float*)d_in[18];
  const float* stp_b = (const float*)d_in[19];
  const float* a1_Wi = (const float*)d_in[20];
  const float* a1_bi = (const float*)d_in[21];
  const float* a1_Wo = (const float*)d_in[22];
  const float* a1_bo = (const float*)d_in[23];
  const float* a2_Wi = (const float*)d_in[24];
  const float* a2_bi = (const float*)d_in[25];
  const float* a2_Wo = (const float*)d_in[26];
  const float* a2_bo = (const float*)d_in[27];
  const float* p1_W = (const float*)d_in[28];
  const float* p1_b = (const float*)d_in[29];
  const float* p2_W = (const float*)d_in[30];
  const float* p2_b = (const float*)d_in[31];
  const float* p3_W = (const float*)d_in[32];
  const float* p3_b = (const float*)d_in[33];

  const int E = in_sizes[2] / 2;
  const int* e_src = eidx;
  const int* e_dst = eidx + E;

  char* p = (char*)d_ws;
  auto alloc = [&](size_t bytes) -> void* {
    void* r = p;
    p += (bytes + 255) & ~(size_t)255;
    return r;
  };
  float* h    = (float*)alloc(sizeof(float) * (size_t)N_NODES * HID);
  float* xl   = (float*)alloc(sizeof(float) * (size_t)N_NODES * HID);
  float* esrc = (float*)alloc(sizeof(float) * (size_t)N_NODES * 4);
  float* edst = (float*)alloc(sizeof(float) * (size_t)N_NODES * 4);
  int* cnt    = (int*)alloc(sizeof(int) * N_NODES);
  int* cur    = (int*)alloc(sizeof(int) * N_NODES);
  int* off    = (int*)alloc(sizeof(int) * (N_NODES + 1));
  int* eadj   = (int*)alloc(sizeof(int) * (size_t)E);
  int* bsum   = (int*)alloc(sizeof(int) * 128);
  float* pooled = (float*)alloc(sizeof(float) * B_GRAPHS * HID);

  hipMemsetAsync(cnt, 0, sizeof(int) * N_NODES, stream);
  hipMemsetAsync(cur, 0, sizeof(int) * N_NODES, stream);

  const int SCAN_BLKS = (N_NODES + 1023) / 1024;  // 98
  ne_kernel<<<N_NODES * HID / 256, 256, 0, stream>>>(x, ne_W, ne_b, h);
  hist_kernel<<<(E + 255) / 256, 256, 0, stream>>>(e_dst, cnt, E);
  scan1_kernel<<<SCAN_BLKS, 1024, 0, stream>>>(cnt, off, bsum, N_NODES);
  scan2_kernel<<<1, 64, 0, stream>>>(bsum, SCAN_BLKS);
  scan3_kernel<<<(N_NODES + 256) / 256, 256, 0, stream>>>(bsum, off, N_NODES, E);
  scatter_kernel<<<(E + 255) / 256, 256, 0, stream>>>(e_src, e_dst, off, cur, eadj, E);

  for (int l = 0; l < L_LAYERS; ++l) {
    gat_xl_kernel<<<(N_NODES + 127) / 128, 256, 0, stream>>>(
        h, gat_W + (size_t)l * HID * HID, gat_asrc + l * HID, gat_adst + l * HID,
        xl, esrc, edst);
    gat_agg_kernel<<<N_NODES / 4, 256, 0, stream>>>(
        xl, esrc, edst, off, eadj, gat_b + l * HID, ln_g + l * HID, ln_b + l * HID, h);
  }
  pool_kernel<<<dim3(B_GRAPHS, 4), 256, 0, stream>>>(h, batch, pooled);

  head_kernel<<<B_GRAPHS, 256, 0, stream>>>(
      pooled, seq_emb, op1_W, op1_b, op2_W, op2_b, sp_W, sp_b, stp_W, stp_b,
      a1_Wi, a1_bi, a1_Wo, a1_bo, a2_Wi, a2_bi, a2_Wo, a2_bo,
      p1_W, p1_b, p2_W, p2_b, p3_W, p3_b, (float*)d_out);
}

// Round 4
// 775.494 us; speedup vs baseline: 2.7729x; 1.1128x over previous
//
#include <hip/hip_runtime.h>
#include <hip/hip_bf16.h>

#define N_NODES 100000
#define NFEAT 9
#define HID 128
#define B_GRAPHS 64
#define SEQ_LEN 768
#define HD 256
#define L_LAYERS 4
#define LN_EPS 1e-5f

__device__ __forceinline__ float lrelu(float v) { return v > 0.f ? v : 0.2f * v; }

__device__ __forceinline__ float wave_sum64(float x) {
#pragma unroll
  for (int o = 32; o >= 1; o >>= 1) x += __shfl_xor(x, o, 64);
  return x;
}

// round-to-nearest-even bf16 pair pack: low16 = bf16(lo), high16 = bf16(hi)
__device__ __forceinline__ unsigned int bf16pair(float lo, float hi) {
  unsigned int ul = __float_as_uint(lo);
  unsigned int uh = __float_as_uint(hi);
  ul = (ul + 0x7fffu + ((ul >> 16) & 1u)) >> 16;
  uh = (uh + 0x7fffu + ((uh >> 16) & 1u)) & 0xffff0000u;
  return ul | uh;
}

// h = relu(x @ ne_W.T + ne_b); thread per (node, col)
__global__ __launch_bounds__(256) void ne_kernel(const float* __restrict__ x,
                                                 const float* __restrict__ W,
                                                 const float* __restrict__ b,
                                                 float* __restrict__ h) {
  int idx = blockIdx.x * 256 + threadIdx.x;
  int n = idx >> 7, c = idx & 127;
  const float* xr = x + n * NFEAT;
  const float* wr = W + c * NFEAT;
  float acc = b[c];
#pragma unroll
  for (int k = 0; k < NFEAT; ++k) acc += xr[k] * wr[k];
  h[idx] = fmaxf(acc, 0.f);
}

__global__ __launch_bounds__(256) void hist_kernel(const int* __restrict__ dst,
                                                   int* __restrict__ cnt, int E) {
  int i = blockIdx.x * 256 + threadIdx.x;
  if (i < E) atomicAdd(&cnt[dst[i]], 1);
}

// hierarchical exclusive scan
__global__ __launch_bounds__(1024) void scan1_kernel(const int* __restrict__ cnt,
                                                     int* __restrict__ off,
                                                     int* __restrict__ bsum, int n) {
  __shared__ int ws[16];
  __shared__ int wx[16];
  int tid = threadIdx.x, lane = tid & 63, w = tid >> 6;
  int i = blockIdx.x * 1024 + tid;
  int v = (i < n) ? cnt[i] : 0;
  int x = v;
#pragma unroll
  for (int o = 1; o < 64; o <<= 1) {
    int t = __shfl_up(x, o, 64);
    if (lane >= o) x += t;
  }
  if (lane == 63) ws[w] = x;
  __syncthreads();
  if (tid == 0) {
    int r = 0;
#pragma unroll
    for (int j = 0; j < 16; ++j) { int t = ws[j]; wx[j] = r; r += t; }
    bsum[blockIdx.x] = r;
  }
  __syncthreads();
  if (i < n) off[i] = wx[w] + x - v;
}

__global__ void scan2_kernel(int* __restrict__ bsum, int nb) {
  int lane = threadIdx.x;
  int i0 = lane * 2, i1 = i0 + 1;
  int a = (i0 < nb) ? bsum[i0] : 0;
  int b = (i1 < nb) ? bsum[i1] : 0;
  int s = a + b, x = s;
#pragma unroll
  for (int o = 1; o < 64; o <<= 1) {
    int t = __shfl_up(x, o, 64);
    if (lane >= o) x += t;
  }
  int excl = x - s;
  if (i0 < nb) bsum[i0] = excl;
  if (i1 < nb) bsum[i1] = excl + a;
}

__global__ __launch_bounds__(256) void scan3_kernel(const int* __restrict__ bsum,
                                                    int* __restrict__ off, int n, int total) {
  int i = blockIdx.x * 256 + threadIdx.x;
  if (i < n) off[i] += bsum[i >> 10];
  else if (i == n) off[i] = total;
}

__global__ __launch_bounds__(256) void scatter_kernel(const int* __restrict__ src,
                                                      const int* __restrict__ dst,
                                                      const int* __restrict__ off,
                                                      int* __restrict__ cur,
                                                      int* __restrict__ eadj, int E) {
  int i = blockIdx.x * 256 + threadIdx.x;
  if (i < E) {
    int d = dst[i];
    int pos = atomicAdd(&cur[d], 1);
    eadj[off[d] + pos] = src[i];
  }
}

// xl = h @ W.T : 128x128 tile per block, 8x8 per thread, K chunked by 32.
// Emits packed bf16 message pairs xlp[node][p] = (col p, col p+64), and fp32 logits.
__global__ __launch_bounds__(256) void gat_xl_kernel(const float* __restrict__ h,
                                                     const float* __restrict__ W,
                                                     const float* __restrict__ asrc,
                                                     const float* __restrict__ adst,
                                                     unsigned int* __restrict__ xlp,
                                                     float* __restrict__ esrc,
                                                     float* __restrict__ edst) {
  __shared__ float As[32][132];
  __shared__ float Ws[32][132];
  const int tid = threadIdx.x;
  const int base = blockIdx.x * 128;
  const int lane = tid & 63;
  const int wv = tid >> 6;
  const int r0 = (wv >> 1) * 64 + (lane >> 3) * 8;
  const int c_lo = (wv & 1) * 32 + (lane & 7) * 4;  // cols c_lo..+3 and c_lo+64..+67
  const int c_hi = c_lo + 64;

  float acc[8][8];  // [node][0..3]=c_lo.., [4..7]=c_hi..
#pragma unroll
  for (int i = 0; i < 8; ++i)
#pragma unroll
    for (int j = 0; j < 8; ++j) acc[i][j] = 0.f;

  for (int k0 = 0; k0 < 128; k0 += 32) {
#pragma unroll
    for (int t = 0; t < 4; ++t) {
      int f4 = tid + t * 256;
      int row = f4 >> 3;
      int kko = (f4 & 7) << 2;
      int gn = base + row;
      if (gn >= N_NODES) gn = N_NODES - 1;
      float4 av = *(const float4*)(h + (size_t)gn * HID + k0 + kko);
      As[kko + 0][row] = av.x;
      As[kko + 1][row] = av.y;
      As[kko + 2][row] = av.z;
      As[kko + 3][row] = av.w;
      float4 wv4 = *(const float4*)(W + (size_t)row * HID + k0 + kko);
      Ws[kko + 0][row] = wv4.x;
      Ws[kko + 1][row] = wv4.y;
      Ws[kko + 2][row] = wv4.z;
      Ws[kko + 3][row] = wv4.w;
    }
    __syncthreads();
#pragma unroll 8
    for (int kk = 0; kk < 32; ++kk) {
      float4 a0 = *(const float4*)&As[kk][r0];
      float4 a1 = *(const float4*)&As[kk][r0 + 4];
      float4 w0 = *(const float4*)&Ws[kk][c_lo];
      float4 w1 = *(const float4*)&Ws[kk][c_hi];
      float a[8] = {a0.x, a0.y, a0.z, a0.w, a1.x, a1.y, a1.z, a1.w};
      float w[8] = {w0.x, w0.y, w0.z, w0.w, w1.x, w1.y, w1.z, w1.w};
#pragma unroll
      for (int i = 0; i < 8; ++i)
#pragma unroll
        for (int j = 0; j < 8; ++j) acc[i][j] += a[i] * w[j];
    }
    __syncthreads();
  }

  float asl[4], ash[4], adl[4], adh[4];
#pragma unroll
  for (int j = 0; j < 4; ++j) {
    asl[j] = asrc[c_lo + j];
    ash[j] = asrc[c_hi + j];
    adl[j] = adst[c_lo + j];
    adh[j] = adst[c_hi + j];
  }
  const int head_lo = (wv & 1);      // c_lo>>5
  const int head_hi = head_lo + 2;   // c_hi>>5
#pragma unroll
  for (int i = 0; i < 8; ++i) {
    int node = base + r0 + i;
    bool ok = node < N_NODES;
    if (ok) {
      unsigned int pk0 = bf16pair(acc[i][0], acc[i][4]);
      unsigned int pk1 = bf16pair(acc[i][1], acc[i][5]);
      unsigned int pk2 = bf16pair(acc[i][2], acc[i][6]);
      unsigned int pk3 = bf16pair(acc[i][3], acc[i][7]);
      *(uint4*)(xlp + (size_t)node * 64 + c_lo) = make_uint4(pk0, pk1, pk2, pk3);
    }
    float psl = 0.f, psh = 0.f, pdl = 0.f, pdh = 0.f;
#pragma unroll
    for (int j = 0; j < 4; ++j) {
      psl += acc[i][j] * asl[j];
      psh += acc[i][4 + j] * ash[j];
      pdl += acc[i][j] * adl[j];
      pdh += acc[i][4 + j] * adh[j];
    }
#pragma unroll
    for (int o = 1; o <= 4; o <<= 1) {
      psl += __shfl_xor(psl, o, 64);
      psh += __shfl_xor(psh, o, 64);
      pdl += __shfl_xor(pdl, o, 64);
      pdh += __shfl_xor(pdh, o, 64);
    }
    if (ok && (lane & 7) == 0) {
      esrc[node * 4 + head_lo] = psl;
      esrc[node * 4 + head_hi] = psh;
      edst[node * 4 + head_lo] = pdl;
      edst[node * 4 + head_hi] = pdh;
    }
  }
}

// single-pass softmax aggregation, 4-edge pipeline, packed-bf16 message gather.
__global__ __launch_bounds__(256) void gat_agg_kernel(const unsigned int* __restrict__ xlp,
                                                      const float* __restrict__ esrc,
                                                      const float* __restrict__ edst,
                                                      const int* __restrict__ off,
                                                      const int* __restrict__ eadj,
                                                      const float* __restrict__ gbias,
                                                      const float* __restrict__ lng,
                                                      const float* __restrict__ lnb,
                                                      float* __restrict__ h) {
  const int tid = threadIdx.x;
  const int lane = tid & 63;
  const int i = blockIdx.x * 4 + (tid >> 6);
  const int hd0 = lane >> 5;

  const float4 ed = *(const float4*)(edst + (size_t)i * 4);
  const float4 e0 = *(const float4*)(esrc + (size_t)i * 4);
  float w0 = __expf(lrelu(e0.x + ed.x));
  float w1 = __expf(lrelu(e0.y + ed.y));
  float w2 = __expf(lrelu(e0.z + ed.z));
  float w3 = __expf(lrelu(e0.w + ed.w));
  float s0 = w0, s1 = w1, s2 = w2, s3 = w3;
  const unsigned int* xp = xlp + lane;
  const unsigned int vi = xp[(size_t)i * 64];
  float accA = __uint_as_float(vi << 16) * (hd0 == 0 ? w0 : w1);
  float accB = __uint_as_float(vi & 0xffff0000u) * (hd0 == 0 ? w2 : w3);
  const int beg = off[i], end = off[i + 1];
  int j = beg;
  for (; j + 4 <= end; j += 4) {
    const int sa = eadj[j + 0];
    const int sb = eadj[j + 1];
    const int sc = eadj[j + 2];
    const int sd = eadj[j + 3];
    const float4 Ea = *(const float4*)(esrc + (size_t)sa * 4);
    const float4 Eb = *(const float4*)(esrc + (size_t)sb * 4);
    const float4 Ec = *(const float4*)(esrc + (size_t)sc * 4);
    const float4 Ed = *(const float4*)(esrc + (size_t)sd * 4);
    const unsigned int va = xp[(size_t)sa * 64];
    const unsigned int vb = xp[(size_t)sb * 64];
    const unsigned int vc = xp[(size_t)sc * 64];
    const unsigned int vd = xp[(size_t)sd * 64];
    float qa0 = __expf(lrelu(Ea.x + ed.x)), qa1 = __expf(lrelu(Ea.y + ed.y));
    float qa2 = __expf(lrelu(Ea.z + ed.z)), qa3 = __expf(lrelu(Ea.w + ed.w));
    float qb0 = __expf(lrelu(Eb.x + ed.x)), qb1 = __expf(lrelu(Eb.y + ed.y));
    float qb2 = __expf(lrelu(Eb.z + ed.z)), qb3 = __expf(lrelu(Eb.w + ed.w));
    float qc0 = __expf(lrelu(Ec.x + ed.x)), qc1 = __expf(lrelu(Ec.y + ed.y));
    float qc2 = __expf(lrelu(Ec.z + ed.z)), qc3 = __expf(lrelu(Ec.w + ed.w));
    float qd0 = __expf(lrelu(Ed.x + ed.x)), qd1 = __expf(lrelu(Ed.y + ed.y));
    float qd2 = __expf(lrelu(Ed.z + ed.z)), qd3 = __expf(lrelu(Ed.w + ed.w));
    s0 += qa0 + qb0 + qc0 + qd0;
    s1 += qa1 + qb1 + qc1 + qd1;
    s2 += qa2 + qb2 + qc2 + qd2;
    s3 += qa3 + qb3 + qc3 + qd3;
    accA += __uint_as_float(va << 16) * (hd0 == 0 ? qa0 : qa1) +
            __uint_as_float(vb << 16) * (hd0 == 0 ? qb0 : qb1) +
            __uint_as_float(vc << 16) * (hd0 == 0 ? qc0 : qc1) +
            __uint_as_float(vd << 16) * (hd0 == 0 ? qd0 : qd1);
    accB += __uint_as_float(va & 0xffff0000u) * (hd0 == 0 ? qa2 : qa3) +
            __uint_as_float(vb & 0xffff0000u) * (hd0 == 0 ? qb2 : qb3) +
            __uint_as_float(vc & 0xffff0000u) * (hd0 == 0 ? qc2 : qc3) +
            __uint_as_float(vd & 0xffff0000u) * (hd0 == 0 ? qd2 : qd3);
  }
  for (; j < end; ++j) {
    const int sc = eadj[j];
    const float4 es = *(const float4*)(esrc + (size_t)sc * 4);
    const unsigned int v = xp[(size_t)sc * 64];
    float q0 = __expf(lrelu(es.x + ed.x));
    float q1 = __expf(lrelu(es.y + ed.y));
    float q2 = __expf(lrelu(es.z + ed.z));
    float q3 = __expf(lrelu(es.w + ed.w));
    s0 += q0; s1 += q1; s2 += q2; s3 += q3;
    accA += __uint_as_float(v << 16) * (hd0 == 0 ? q0 : q1);
    accB += __uint_as_float(v & 0xffff0000u) * (hd0 == 0 ? q2 : q3);
  }
  float dA = (hd0 == 0 ? s0 : s1) + 1e-16f;
  float dB = (hd0 == 0 ? s2 : s3) + 1e-16f;
  float o0 = accA / dA + gbias[lane];
  float o1 = accB / dB + gbias[lane + 64];
  float mu = wave_sum64(o0 + o1) * (1.f / 128.f);
  float d0 = o0 - mu, d1 = o1 - mu;
  float var = wave_sum64(d0 * d0 + d1 * d1) * (1.f / 128.f);
  float r = rsqrtf(var + LN_EPS);
  float hn0 = fmaxf(d0 * r * lng[lane] + lnb[lane], 0.f);
  float hn1 = fmaxf(d1 * r * lng[lane + 64] + lnb[lane + 64], 0.f);
  h[(size_t)i * HID + lane] += hn0;
  h[(size_t)i * HID + 64 + lane] += hn1;
}

__device__ __forceinline__ int lower_bound_dev(const int* a, int n, int v) {
  int lo = 0, hi = n;
  while (lo < hi) {
    int mid = (lo + hi) >> 1;
    if (a[mid] < v) lo = mid + 1; else hi = mid;
  }
  return lo;
}

// per-batch mean pool; grid (B, 4)
__global__ __launch_bounds__(256) void pool_kernel(const float* __restrict__ h,
                                                   const int* __restrict__ batch,
                                                   float* __restrict__ pooled) {
  __shared__ float red[256];
  int b = blockIdx.x, tid = threadIdx.x;
  int start = lower_bound_dev(batch, N_NODES, b);
  int end = lower_bound_dev(batch, N_NODES, b + 1);
  int cl = tid & 31, g = tid >> 5;
  int c = cl + blockIdx.y * 32;
  float acc = 0.f;
  for (int n = start + g; n < end; n += 8) acc += h[(size_t)n * HID + c];
  red[tid] = acc;
  __syncthreads();
  if (g == 0) {
    float tot = 0.f;
#pragma unroll
    for (int k = 0; k < 8; ++k) tot += red[cl + 32 * k];
    float cntf = fmaxf((float)(end - start), 1.f);
    pooled[b * HID + c] = tot / cntf;
  }
}

// One wave per output element (m,c); lane-split K; two independent fused stages.
__global__ __launch_bounds__(256) void gemv2_kernel(
    const float* __restrict__ A1, int lda1, const float* __restrict__ W1,
    const float* __restrict__ b1, float* __restrict__ O1, int ldo1,
    int sh1, int K1, int relu1,
    const float* __restrict__ A2, int lda2, const float* __restrict__ W2,
    const float* __restrict__ b2, float* __restrict__ O2, int ldo2,
    int sh2, int K2, int relu2, int nw1, int nwTot) {
  int gw = (blockIdx.x * 256 + threadIdx.x) >> 6;
  int lane = threadIdx.x & 63;
  if (gw >= nwTot) return;
  const float *A, *W, *b;
  float* O;
  int lda, ldo, K, relu, m, c;
  if (gw < nw1) {
    A = A1; W = W1; b = b1; O = O1; lda = lda1; ldo = ldo1; K = K1; relu = relu1;
    m = gw >> sh1; c = gw & ((1 << sh1) - 1);
  } else {
    int g2 = gw - nw1;
    A = A2; W = W2; b = b2; O = O2; lda = lda2; ldo = ldo2; K = K2; relu = relu2;
    m = g2 >> sh2; c = g2 & ((1 << sh2) - 1);
  }
  const float* a = A + (size_t)m * lda;
  const float* w = W + (size_t)c * K;
  float acc = 0.f;
  for (int k = lane * 2; k < K; k += 128) {
    float2 av = *(const float2*)(a + k);
    float2 wv = *(const float2*)(w + k);
    acc += av.x * wv.x + av.y * wv.y;
  }
  acc = wave_sum64(acc);
  if (lane == 0) {
    acc += b[c];
    if (relu) acc = fmaxf(acc, 0.f);
    O[(size_t)m * ldo + c] = acc;
  }
}

// z1 = relu([att1|att2|seqh|strh] @ p1_W.T + p1_b); wave per (m,c)
__global__ __launch_bounds__(256) void z1_kernel(const float* __restrict__ att1,
                                                 const float* __restrict__ att2,
                                                 const float* __restrict__ seqh,
                                                 const float* __restrict__ strh,
                                                 const float* __restrict__ p1_W,
                                                 const float* __restrict__ p1_b,
                                                 float* __restrict__ z1) {
  int gw = (blockIdx.x * 256 + threadIdx.x) >> 6;
  int lane = threadIdx.x & 63;
  int m = gw >> 8, c = gw & 255;
  const float* segs[4] = {att1 + m * HD, att2 + m * HD, seqh + m * HD, strh + m * HD};
  const float* w = p1_W + (size_t)c * (4 * HD);
  float acc = 0.f;
#pragma unroll
  for (int s = 0; s < 4; ++s) {
    const float* a = segs[s];
    const float* ws = w + s * HD;
#pragma unroll
    for (int k = lane * 2; k < HD; k += 128) {
      float2 av = *(const float2*)(a + k);
      float2 wv = *(const float2*)(ws + k);
      acc += av.x * wv.x + av.y * wv.y;
    }
  }
  acc = wave_sum64(acc);
  if (lane == 0) z1[m * HD + c] = fmaxf(acc + p1_b[c], 0.f);
}

extern "C" void kernel_launch(void* const* d_in, const int* in_sizes, int n_in,
                              void* d_out, int out_size, void* d_ws, size_t ws_size,
                              hipStream_t stream) {
  const float* seq_emb = (const float*)d_in[0];
  const float* x       = (const float*)d_in[1];
  const int* eidx      = (const int*)d_in[2];
  const int* batch     = (const int*)d_in[3];
  const float* ne_W = (const float*)d_in[4];
  const float* ne_b = (const float*)d_in[5];
  const float* gat_W = (const float*)d_in[6];
  const float* gat_asrc = (const float*)d_in[7];
  const float* gat_adst = (const float*)d_in[8];
  const float* gat_b = (const float*)d_in[9];
  const float* ln_g = (const float*)d_in[10];
  const float* ln_b = (const float*)d_in[11];
  const float* op1_W = (const float*)d_in[12];
  const float* op1_b = (const float*)d_in[13];
  const float* op2_W = (const float*)d_in[14];
  const float* op2_b = (const float*)d_in[15];
  const float* sp_W = (const float*)d_in[16];
  const float* sp_b = (const float*)d_in[17];
  const float* stp_W = (const float*)d_in[18];
  const float* stp_b = (const float*)d_in[19];
  const float* a1_Wi = (const float*)d_in[20];
  const float* a1_bi = (const float*)d_in[21];
  const float* a1_Wo = (const float*)d_in[22];
  const float* a1_bo = (const float*)d_in[23];
  const float* a2_Wi = (const float*)d_in[24];
  const float* a2_bi = (const float*)d_in[25];
  const float* a2_Wo = (const float*)d_in[26];
  const float* a2_bo = (const float*)d_in[27];
  const float* p1_W = (const float*)d_in[28];
  const float* p1_b = (const float*)d_in[29];
  const float* p2_W = (const float*)d_in[30];
  const float* p2_b = (const float*)d_in[31];
  const float* p3_W = (const float*)d_in[32];
  const float* p3_b = (const float*)d_in[33];

  const int E = in_sizes[2] / 2;
  const int* e_src = eidx;
  const int* e_dst = eidx + E;

  char* p = (char*)d_ws;
  auto alloc = [&](size_t bytes) -> void* {
    void* r = p;
    p += (bytes + 255) & ~(size_t)255;
    return r;
  };
  float* h    = (float*)alloc(sizeof(float) * (size_t)N_NODES * HID);
  unsigned int* xlp = (unsigned int*)alloc(sizeof(unsigned int) * (size_t)N_NODES * 64);
  float* esrc = (float*)alloc(sizeof(float) * (size_t)N_NODES * 4);
  float* edst = (float*)alloc(sizeof(float) * (size_t)N_NODES * 4);
  int* cnt    = (int*)alloc(sizeof(int) * N_NODES);
  int* cur    = (int*)alloc(sizeof(int) * N_NODES);
  int* off    = (int*)alloc(sizeof(int) * (N_NODES + 1));
  int* eadj   = (int*)alloc(sizeof(int) * (size_t)E);
  int* bsum   = (int*)alloc(sizeof(int) * 128);
  float* pooled = (float*)alloc(sizeof(float) * B_GRAPHS * HID);
  float* t1B   = (float*)alloc(sizeof(float) * B_GRAPHS * HID);
  float* sembB = (float*)alloc(sizeof(float) * B_GRAPHS * HID);
  float* seqhB = (float*)alloc(sizeof(float) * B_GRAPHS * HD);
  float* strhB = (float*)alloc(sizeof(float) * B_GRAPHS * HD);
  float* v1B   = (float*)alloc(sizeof(float) * B_GRAPHS * HD);
  float* v2B   = (float*)alloc(sizeof(float) * B_GRAPHS * HD);
  float* att1B = (float*)alloc(sizeof(float) * B_GRAPHS * HD);
  float* att2B = (float*)alloc(sizeof(float) * B_GRAPHS * HD);
  float* z1B   = (float*)alloc(sizeof(float) * B_GRAPHS * HD);
  float* z2B   = (float*)alloc(sizeof(float) * B_GRAPHS * (HD / 2));

  hipMemsetAsync(cnt, 0, sizeof(int) * N_NODES, stream);
  hipMemsetAsync(cur, 0, sizeof(int) * N_NODES, stream);

  const int SCAN_BLKS = (N_NODES + 1023) / 1024;  // 98
  ne_kernel<<<N_NODES * HID / 256, 256, 0, stream>>>(x, ne_W, ne_b, h);
  hist_kernel<<<(E + 255) / 256, 256, 0, stream>>>(e_dst, cnt, E);
  scan1_kernel<<<SCAN_BLKS, 1024, 0, stream>>>(cnt, off, bsum, N_NODES);
  scan2_kernel<<<1, 64, 0, stream>>>(bsum, SCAN_BLKS);
  scan3_kernel<<<(N_NODES + 256) / 256, 256, 0, stream>>>(bsum, off, N_NODES, E);
  scatter_kernel<<<(E + 255) / 256, 256, 0, stream>>>(e_src, e_dst, off, cur, eadj, E);

  for (int l = 0; l < L_LAYERS; ++l) {
    gat_xl_kernel<<<(N_NODES + 127) / 128, 256, 0, stream>>>(
        h, gat_W + (size_t)l * HID * HID, gat_asrc + l * HID, gat_adst + l * HID,
        xlp, esrc, edst);
    gat_agg_kernel<<<N_NODES / 4, 256, 0, stream>>>(
        xlp, esrc, edst, off, eadj, gat_b + l * HID, ln_g + l * HID, ln_b + l * HID, h);
  }
  pool_kernel<<<dim3(B_GRAPHS, 4), 256, 0, stream>>>(h, batch, pooled);

  // ---- head: 8 dependency levels, wave-per-output ----
  const float* a1_Wv = a1_Wi + 2 * HD * HD;
  const float* a1_bv = a1_bi + 2 * HD;
  const float* a2_Wv = a2_Wi + 2 * HD * HD;
  const float* a2_bv = a2_bi + 2 * HD;
  auto nblk = [](int waves) { return (unsigned)((waves + 3) / 4); };

  // L1: seqh = seq_emb@sp_W.T+b ; t1 = relu(pooled@op1.T+b)
  {
    int nw1 = B_GRAPHS * HD, nwT = nw1 + B_GRAPHS * HID;
    gemv2_kernel<<<nblk(nwT), 256, 0, stream>>>(
        seq_emb, SEQ_LEN, sp_W, sp_b, seqhB, HD, 8, SEQ_LEN, 0,
        pooled, HID, op1_W, op1_b, t1B, HID, 7, HID, 1, nw1, nwT);
  }
  // L2: v2 = seqh@a2_Wv.T+b ; semb = t1@op2.T+b
  {
    int nw1 = B_GRAPHS * HD, nwT = nw1 + B_GRAPHS * HID;
    gemv2_kernel<<<nblk(nwT), 256, 0, stream>>>(
        seqhB, HD, a2_Wv, a2_bv, v2B, HD, 8, HD, 0,
        t1B, HID, op2_W, op2_b, sembB, HID, 7, HID, 0, nw1, nwT);
  }
  // L3: att2 = v2@a2_Wo.T+b ; strh = semb@stp.T+b
  {
    int nw1 = B_GRAPHS * HD, nwT = nw1 + B_GRAPHS * HD;
    gemv2_kernel<<<nblk(nwT), 256, 0, stream>>>(
        v2B, HD, a2_Wo, a2_bo, att2B, HD, 8, HD, 0,
        sembB, HID, stp_W, stp_b, strhB, HD, 8, HID, 0, nw1, nwT);
  }
  // L4: v1 = strh@a1_Wv.T+b
  {
    int nwT = B_GRAPHS * HD;
    gemv2_kernel<<<nblk(nwT), 256, 0, stream>>>(
        strhB, HD, a1_Wv, a1_bv, v1B, HD, 8, HD, 0,
        nullptr, 0, nullptr, nullptr, nullptr, 0, 0, 0, 0, nwT, nwT);
  }
  // L5: att1 = v1@a1_Wo.T+b
  {
    int nwT = B_GRAPHS * HD;
    gemv2_kernel<<<nblk(nwT), 256, 0, stream>>>(
        v1B, HD, a1_Wo, a1_bo, att1B, HD, 8, HD, 0,
        nullptr, 0, nullptr, nullptr, nullptr, 0, 0, 0, 0, nwT, nwT);
  }
  // L6: z1
  z1_kernel<<<nblk(B_GRAPHS * HD), 256, 0, stream>>>(att1B, att2B, seqhB, strhB, p1_W, p1_b, z1B);
  // L7: z2 = relu(z1@p2.T+b)
  {
    int nwT = B_GRAPHS * (HD / 2);
    gemv2_kernel<<<nblk(nwT), 256, 0, stream>>>(
        z1B, HD, p2_W, p2_b, z2B, HD / 2, 7, HD, 1,
        nullptr, 0, nullptr, nullptr, nullptr, 0, 0, 0, 0, nwT, nwT);
  }
  // L8: out = z2@p3.T+b  (Nc=1, sh=0)
  {
    int nwT = B_GRAPHS;
    gemv2_kernel<<<nblk(nwT), 256, 0, stream>>>(
        z2B, HD / 2, p3_W, p3_b, (float*)d_out, 1, 0, HD / 2, 0,
        nullptr, 0, nullptr, nullptr, nullptr, 0, 0, 0, 0, nwT, nwT);
  }
}